// Round 9
// baseline (378.892 us; speedup 1.0000x reference)
//
#include <hip/hip_runtime.h>
#include <math.h>

#define HWPIX 3136   // 56*56
#define NC    256
#define NCNEW 128
#define NH    16     // C/R

// ---------------------------------------------------------------------------
// numpy pairwise block sum (8 <= n <= 128) — exact np arithmetic order.
// ---------------------------------------------------------------------------
__device__ __forceinline__ float np_block_sum(const float* __restrict__ a, int n) {
    float r0=a[0],r1=a[1],r2=a[2],r3=a[3],r4=a[4],r5=a[5],r6=a[6],r7=a[7];
    int i = 8;
    const int lim = n - (n & 7);
    for (; i < lim; i += 8) {
        r0 += a[i+0]; r1 += a[i+1]; r2 += a[i+2]; r3 += a[i+3];
        r4 += a[i+4]; r5 += a[i+5]; r6 += a[i+6]; r7 += a[i+7];
    }
    float res = ((r0 + r1) + (r2 + r3)) + ((r4 + r5) + (r6 + r7));
    for (; i < n; ++i) res += a[i];
    return res;
}

// ---------------------------------------------------------------------------
// Kernel 1: per-plane np.float32 mean (bit-exact) + last-block-per-batch
// MLP/sigmoid/rank fusion. NO spinning: each block does release-fence +
// atomicInc(cnt[b], 255); the 256th arriver (old==254 — holds from 0xAA
// poison AND in steady state, since atomicInc wraps to 255 each replay)
// acquire-fences and computes batch b's excitation with its 64 lanes.
// Deadlock-free at any occupancy; round-8 showed spin syncs are fatal here.
// ---------------------------------------------------------------------------
__global__ __launch_bounds__(64) void k_mean_mlp(const float* __restrict__ x,
                                                 const float* __restrict__ w1,
                                                 const float* __restrict__ b1,
                                                 const float* __restrict__ w2,
                                                 const float* __restrict__ b2,
                                                 float* __restrict__ s_ws,
                                                 float* __restrict__ gate_w,
                                                 int* __restrict__ idx_w,
                                                 unsigned int* __restrict__ cnt) {
    const int plane = blockIdx.x;  // b*256 + c
    const int t = threadIdx.x;
    __shared__ float pl[HWPIX];    // 12.5 KB; reused as s/h/g scratch in MLP

    // ---- mean (identical to round-6 passing version) ----
    const float4* src4 = reinterpret_cast<const float4*>(x + (size_t)plane * HWPIX);
    float4 va[13];
    #pragma unroll
    for (int i = 0; i < 12; ++i) va[i] = src4[i * 64 + t];
    {   int idx = 768 + t; if (idx > 783) idx = 783;
        va[12] = src4[idx];
    }
    #pragma unroll
    for (int i = 0; i < 12; ++i)
        *reinterpret_cast<float4*>(&pl[(i * 64 + t) * 4]) = va[i];
    if (t < 16)
        *reinterpret_cast<float4*>(&pl[(768 + t) * 4]) = va[12];
    __syncthreads();

    const int m    = t >> 1;
    const int base = 98 * m + ((t & 1) ? 48 : 0);
    const int n    = (t & 1) ? 50 : 48;
    float v = np_block_sum(pl + base, n);

    #pragma unroll
    for (int mask = 1; mask <= 32; mask <<= 1)
        v += __shfl_xor(v, mask, 64);

    const int b = plane >> 8;
    if (t == 0) s_ws[plane] = v / 3136.0f;

    // ---- arrival protocol ----
    __threadfence();                       // release s_ws store (device scope)
    unsigned int old = 0;
    if (t == 0) old = atomicInc(&cnt[b], 255u);
    old = (unsigned int)__shfl((int)old, 0, 64);
    if (old != 254u) return;               // not the last arriver of batch b
    __threadfence();                       // acquire the other 255 s stores

    // ---- MLP + sigmoid + exact stable rank for batch b (one wave) ----
    float* sh_s = pl;            // 256
    float* sh_h = pl + NC;       // 16
    float* sh_g = pl + NC + NH;  // 256

    // stage s[b,*] into LDS (coalesced float4)
    *reinterpret_cast<float4*>(&sh_s[4 * t]) =
        reinterpret_cast<const float4*>(s_ws + b * NC)[t];
    // one wave: ds ordering via lgkmcnt, no barrier needed anywhere below

    if (t < NH) {
        float acc = 0.0f;
        #pragma unroll 64
        for (int k = 0; k < NC; ++k)
            acc = fmaf(sh_s[k], w1[t * NC + k], acc);   // exact seq-k chain
        float hp = acc + b1[t];                          // bias added after
        sh_h[t] = fmaxf(hp, 0.0f);                       // relu
    }

    // stage 2: each lane handles channels t, t+64, t+128, t+192
    float gq[4];
    #pragma unroll
    for (int q = 0; q < 4; ++q) {
        const int c = t + 64 * q;
        float acc = 0.0f;
        #pragma unroll
        for (int j = 0; j < NH; ++j)
            acc = fmaf(sh_h[j], w2[c * NH + j], acc);
        const float z  = acc + b2[c];
        const float ef = (float)exp((double)(-z));  // ~cr f32 exp
        const float g  = 1.0f / (1.0f + ef);
        gq[q] = g;
        sh_g[c] = g;
    }

    // exact stable rank (descending, lower index wins ties)
    int rq[4] = {0, 0, 0, 0};
    for (int k = 0; k < NC; ++k) {
        const float gk = sh_g[k];
        #pragma unroll
        for (int q = 0; q < 4; ++q) {
            const int c = t + 64 * q;
            rq[q] += (gk > gq[q]) || (gk == gq[q] && k < c);
        }
    }
    #pragma unroll
    for (int q = 0; q < 4; ++q) {
        if (rq[q] < NCNEW) {
            gate_w[b * NCNEW + rq[q]] = gq[q];
            idx_w[b * NCNEW + rq[q]]  = t + 64 * q;
        }
    }
}

// ---------------------------------------------------------------------------
// Kernel 2 (round-6 best): gather selected channel planes, scale by gate
// (f32 mul, bitwise = reference). 256 threads per output plane.
// ---------------------------------------------------------------------------
__global__ __launch_bounds__(256) void k_gather(const float* __restrict__ x,
                                                const float* __restrict__ gate,
                                                const int* __restrict__ idx,
                                                float* __restrict__ out) {
    const int bid = blockIdx.x;      // b*128 + j
    const int b = bid >> 7;
    const int c = idx[bid];
    const float g = gate[bid];

    const float4* src = reinterpret_cast<const float4*>(
        x + ((size_t)(b * NC + c)) * HWPIX);
    float4* dst = reinterpret_cast<float4*>(out + (size_t)bid * HWPIX);

    const int t = threadIdx.x;
    float4 v;
    v = src[t];       v.x *= g; v.y *= g; v.z *= g; v.w *= g; dst[t]       = v;
    v = src[t + 256]; v.x *= g; v.y *= g; v.z *= g; v.w *= g; dst[t + 256] = v;
    v = src[t + 512]; v.x *= g; v.y *= g; v.z *= g; v.w *= g; dst[t + 512] = v;
    if (t < 16) {
        v = src[t + 768]; v.x *= g; v.y *= g; v.z *= g; v.w *= g; dst[t + 768] = v;
    }
}

// ---------------------------------------------------------------------------
extern "C" void kernel_launch(void* const* d_in, const int* in_sizes, int n_in,
                              void* d_out, int out_size, void* d_ws, size_t ws_size,
                              hipStream_t stream) {
    const float* x  = (const float*)d_in[0];
    const float* w1 = (const float*)d_in[1];
    const float* b1 = (const float*)d_in[2];
    const float* w2 = (const float*)d_in[3];
    const float* b2 = (const float*)d_in[4];
    float* out = (float*)d_out;

    // ws: s (32 KB) | gate (16 KB) | idx (16 KB) | cnt (128 B)
    char* ws = (char*)d_ws;
    float* s_ws   = (float*)ws;
    float* gate_w = (float*)(ws + 32768);
    int*   idx_w  = (int*)(ws + 32768 + 16384);
    unsigned int* cnt = (unsigned int*)(ws + 32768 + 16384 + 16384);

    k_mean_mlp<<<32 * NC, 64, 0, stream>>>(x, w1, b1, w2, b2,
                                           s_ws, gate_w, idx_w, cnt);
    k_gather<<<32 * NCNEW, 256, 0, stream>>>(x, gate_w, idx_w, out);
}

// Round 10
// 90.689 us; speedup vs baseline: 4.1779x; 4.1779x over previous
//
#include <hip/hip_runtime.h>
#include <math.h>

#define HWPIX 3136   // 56*56
#define NC    256
#define NCNEW 128
#define NH    16     // C/R

// ---------------------------------------------------------------------------
// numpy pairwise block sum (8 <= n <= 128) — exact np arithmetic order.
// ---------------------------------------------------------------------------
__device__ __forceinline__ float np_block_sum(const float* __restrict__ a, int n) {
    float r0=a[0],r1=a[1],r2=a[2],r3=a[3],r4=a[4],r5=a[5],r6=a[6],r7=a[7];
    int i = 8;
    const int lim = n - (n & 7);
    for (; i < lim; i += 8) {
        r0 += a[i+0]; r1 += a[i+1]; r2 += a[i+2]; r3 += a[i+3];
        r4 += a[i+4]; r5 += a[i+5]; r6 += a[i+6]; r7 += a[i+7];
    }
    float res = ((r0 + r1) + (r2 + r3)) + ((r4 + r5) + (r6 + r7));
    for (; i < n; ++i) res += a[i];
    return res;
}

// ---------------------------------------------------------------------------
// Kernel 1 (round-6 verbatim, passing): per-plane bitwise np.float32 mean.
// One 64-thread block per plane; straight-line staging; pairwise tree via
// leaf blocks + xor-butterfly.
// ---------------------------------------------------------------------------
__global__ __launch_bounds__(64) void k_mean(const float* __restrict__ x,
                                             float* __restrict__ s) {
    const int plane = blockIdx.x;  // b*256 + c
    const int t = threadIdx.x;
    __shared__ float pl[HWPIX];

    const float4* src4 = reinterpret_cast<const float4*>(x + (size_t)plane * HWPIX);

    float4 va[13];
    #pragma unroll
    for (int i = 0; i < 12; ++i) va[i] = src4[i * 64 + t];
    {   int idx = 768 + t; if (idx > 783) idx = 783;
        va[12] = src4[idx];
    }
    #pragma unroll
    for (int i = 0; i < 12; ++i)
        *reinterpret_cast<float4*>(&pl[(i * 64 + t) * 4]) = va[i];
    if (t < 16)
        *reinterpret_cast<float4*>(&pl[(768 + t) * 4]) = va[12];
    __syncthreads();

    const int m    = t >> 1;
    const int base = 98 * m + ((t & 1) ? 48 : 0);
    const int n    = (t & 1) ? 50 : 48;
    float v = np_block_sum(pl + base, n);

    #pragma unroll
    for (int mask = 1; mask <= 32; mask <<= 1)
        v += __shfl_xor(v, mask, 64);

    if (t == 0) s[plane] = v / 3136.0f;
}

// ---------------------------------------------------------------------------
// Kernel 2: fused MLP + top-k + gather. One block per OUTPUT plane (b,j).
// Each block redundantly recomputes batch b's excitation (bit-exact
// round-6 arithmetic: LDS-staged operands, seq-k fmaf chains, cr-exp
// sigmoid, exact stable rank) and selects the channel whose rank == j.
// Redundancy is pure VALU hidden under the gather's memory phase; it
// removes one kernel dispatch + its ~5us overhead with ZERO cross-block
// communication (rounds 8/9 showed device-scope sync at block scale is
// fatal on gfx950 — the kernel boundary is the only cheap global barrier).
// ---------------------------------------------------------------------------
__global__ __launch_bounds__(256) void k_mlp_gather(const float* __restrict__ x,
                                                    const float* __restrict__ w1,
                                                    const float* __restrict__ b1,
                                                    const float* __restrict__ w2,
                                                    const float* __restrict__ b2,
                                                    const float* __restrict__ s_ws,
                                                    float* __restrict__ out) {
    const int bid = blockIdx.x;      // b*128 + j
    const int b   = bid >> 7;
    const int j   = bid & 127;
    const int tid = threadIdx.x;

    __shared__ float sh_s[NC];
    __shared__ float sh_w1t[NC][NH];   // transposed [k][jj] (16 KB)
    __shared__ float sh_w2[NC * NH];   // row-major [c][jj]  (16 KB)
    __shared__ float sh_h[NH];
    __shared__ float sh_g[NC];
    __shared__ float sel_g;
    __shared__ int   sel_c;

    // prefetch biases (hide global latency under staging)
    const float bias2 = b2[tid];
    float bias1 = 0.0f;
    if (tid < NH) bias1 = b1[tid];

    // coalesced staging: w1 + w2 are 1024 float4 each; L2/L1-hot
    #pragma unroll
    for (int i = 0; i < 4; ++i) {
        const int f4 = i * 256 + tid;
        float4 v = reinterpret_cast<const float4*>(w1)[f4];
        const int base = f4 * 4;        // flat = jj*256 + k
        const int jj = base >> 8;
        const int k  = base & 255;
        sh_w1t[k+0][jj] = v.x; sh_w1t[k+1][jj] = v.y;
        sh_w1t[k+2][jj] = v.z; sh_w1t[k+3][jj] = v.w;
        reinterpret_cast<float4*>(sh_w2)[f4] =
            reinterpret_cast<const float4*>(w2)[f4];
    }
    if (tid < 64)
        reinterpret_cast<float4*>(sh_s)[tid] =
            reinterpret_cast<const float4*>(s_ws + b * NC)[tid];
    __syncthreads();

    if (tid < NH) {
        float acc = 0.0f;
        #pragma unroll 16
        for (int k = 0; k < NC; ++k)
            acc = fmaf(sh_s[k], sh_w1t[k][tid], acc);   // exact seq-k chain
        float hp = acc + bias1;                          // bias added after
        sh_h[tid] = fmaxf(hp, 0.0f);                     // relu
    }
    __syncthreads();

    float acc = 0.0f;
    #pragma unroll
    for (int jj = 0; jj < NH; ++jj)
        acc = fmaf(sh_h[jj], sh_w2[tid * NH + jj], acc);
    const float z  = acc + bias2;
    const float ef = (float)exp((double)(-z));  // ~correctly-rounded f32 exp
    const float g  = 1.0f / (1.0f + ef);        // f32 add, f32 div
    sh_g[tid] = g;
    __syncthreads();

    // exact stable rank (descending, lower index wins ties) — a permutation
    int r = 0;
    #pragma unroll 8
    for (int k = 0; k < NC; ++k) {
        const float gk = sh_g[k];
        r += (gk > g) || (gk == g && k < tid);
    }
    if (r == j) { sel_g = g; sel_c = tid; }   // exactly one thread matches
    __syncthreads();

    const int   c  = sel_c;
    const float gg = sel_g;

    // ---- gather + scale (round-6 body, bit-exact f32 mul) ----
    const float4* src = reinterpret_cast<const float4*>(
        x + ((size_t)(b * NC + c)) * HWPIX);
    float4* dst = reinterpret_cast<float4*>(out + (size_t)bid * HWPIX);

    float4 v;
    v = src[tid];       v.x *= gg; v.y *= gg; v.z *= gg; v.w *= gg; dst[tid]       = v;
    v = src[tid + 256]; v.x *= gg; v.y *= gg; v.z *= gg; v.w *= gg; dst[tid + 256] = v;
    v = src[tid + 512]; v.x *= gg; v.y *= gg; v.z *= gg; v.w *= gg; dst[tid + 512] = v;
    if (tid < 16) {
        v = src[tid + 768]; v.x *= gg; v.y *= gg; v.z *= gg; v.w *= gg; dst[tid + 768] = v;
    }
}

// ---------------------------------------------------------------------------
extern "C" void kernel_launch(void* const* d_in, const int* in_sizes, int n_in,
                              void* d_out, int out_size, void* d_ws, size_t ws_size,
                              hipStream_t stream) {
    const float* x  = (const float*)d_in[0];
    const float* w1 = (const float*)d_in[1];
    const float* b1 = (const float*)d_in[2];
    const float* w2 = (const float*)d_in[3];
    const float* b2 = (const float*)d_in[4];
    float* out = (float*)d_out;

    float* s_ws = (float*)d_ws;   // 8192 f32

    k_mean<<<32 * NC, 64, 0, stream>>>(x, s_ws);
    k_mlp_gather<<<32 * NCNEW, 256, 0, stream>>>(x, w1, b1, w2, b2, s_ws, out);
}

// Round 11
// 65.589 us; speedup vs baseline: 5.7768x; 1.3827x over previous
//
#include <hip/hip_runtime.h>
#include <math.h>

#define HWPIX 3136   // 56*56
#define NC    256
#define NCNEW 128
#define NH    16     // C/R

// ---------------------------------------------------------------------------
// numpy pairwise block sum (8 <= n <= 128) — exact np arithmetic order.
// ---------------------------------------------------------------------------
__device__ __forceinline__ float np_block_sum(const float* __restrict__ a, int n) {
    float r0=a[0],r1=a[1],r2=a[2],r3=a[3],r4=a[4],r5=a[5],r6=a[6],r7=a[7];
    int i = 8;
    const int lim = n - (n & 7);
    for (; i < lim; i += 8) {
        r0 += a[i+0]; r1 += a[i+1]; r2 += a[i+2]; r3 += a[i+3];
        r4 += a[i+4]; r5 += a[i+5]; r6 += a[i+6]; r7 += a[i+7];
    }
    float res = ((r0 + r1) + (r2 + r3)) + ((r4 + r5) + (r6 + r7));
    for (; i < n; ++i) res += a[i];
    return res;
}

// ---------------------------------------------------------------------------
// Kernel 1 (round-6 verbatim, passing, ~15us = HBM floor): per-plane
// bitwise np.float32 mean. One 64-thread block per plane.
// ---------------------------------------------------------------------------
__global__ __launch_bounds__(64) void k_mean(const float* __restrict__ x,
                                             float* __restrict__ s) {
    const int plane = blockIdx.x;  // b*256 + c
    const int t = threadIdx.x;
    __shared__ float pl[HWPIX];

    const float4* src4 = reinterpret_cast<const float4*>(x + (size_t)plane * HWPIX);

    float4 va[13];
    #pragma unroll
    for (int i = 0; i < 12; ++i) va[i] = src4[i * 64 + t];
    {   int idx = 768 + t; if (idx > 783) idx = 783;
        va[12] = src4[idx];
    }
    #pragma unroll
    for (int i = 0; i < 12; ++i)
        *reinterpret_cast<float4*>(&pl[(i * 64 + t) * 4]) = va[i];
    if (t < 16)
        *reinterpret_cast<float4*>(&pl[(768 + t) * 4]) = va[12];
    __syncthreads();

    const int m    = t >> 1;
    const int base = 98 * m + ((t & 1) ? 48 : 0);
    const int n    = (t & 1) ? 50 : 48;
    float v = np_block_sum(pl + base, n);

    #pragma unroll
    for (int mask = 1; mask <= 32; mask <<= 1)
        v += __shfl_xor(v, mask, 64);

    if (t == 0) s[plane] = v / 3136.0f;
}

// ---------------------------------------------------------------------------
// Kernel 2: fused MLP + top-k + gather, one block per OUTPUT plane (b,j).
// R10 retry with the redundancy made cheap: NO w1/w2 LDS staging (R10's
// sh_w1t transposed writes were 16-way bank-conflicted = 1.7e7 conflict
// cycles; and 32KB LDS capped occupancy at 4 blocks/CU). w1/w2 are 32KB
// total -> L2-hot broadcast reads. LDS now 2.3KB -> ~16 blocks/CU to
// hide the dependent fmaf chains. Arithmetic order is byte-identical to
// the passing R10/R6 code -> bit-exact gates and selection.
// ---------------------------------------------------------------------------
__global__ __launch_bounds__(256) void k_mlp_gather(const float* __restrict__ x,
                                                    const float* __restrict__ w1,
                                                    const float* __restrict__ b1,
                                                    const float* __restrict__ w2,
                                                    const float* __restrict__ b2,
                                                    const float* __restrict__ s_ws,
                                                    float* __restrict__ out) {
    const int bid = blockIdx.x;      // b*128 + j
    const int b   = bid >> 7;
    const int j   = bid & 127;
    const int tid = threadIdx.x;

    __shared__ float sh_s[NC];     // 1 KB
    __shared__ float sh_h[NH];     // 64 B
    __shared__ float sh_g[NC];     // 1 KB
    __shared__ float sel_g;
    __shared__ int   sel_c;

    // prefetch bias2 + this thread's w2 row (exact j-order consumption later)
    const float bias2 = b2[tid];
    float4 w2r[4];
    #pragma unroll
    for (int q = 0; q < 4; ++q)
        w2r[q] = reinterpret_cast<const float4*>(w2)[tid * 4 + q];

    // stage s[b,*] into LDS (coalesced float4)
    if (tid < 64)
        reinterpret_cast<float4*>(sh_s)[tid] =
            reinterpret_cast<const float4*>(s_ws + b * NC)[tid];
    __syncthreads();

    // ---- stage 1: 16 lanes, exact seq-k fmaf chain, w1 row from global ----
    if (tid < NH) {
        const float4* w1r = reinterpret_cast<const float4*>(w1 + tid * NC);
        float acc = 0.0f;
        for (int kb = 0; kb < 8; ++kb) {        // 8 batches of 32 k-values
            float4 wv[8];
            #pragma unroll
            for (int i = 0; i < 8; ++i) wv[i] = w1r[kb * 8 + i];  // 8 loads in flight
            #pragma unroll
            for (int i = 0; i < 8; ++i) {
                const int k = kb * 32 + i * 4;
                acc = fmaf(sh_s[k+0], wv[i].x, acc);
                acc = fmaf(sh_s[k+1], wv[i].y, acc);
                acc = fmaf(sh_s[k+2], wv[i].z, acc);
                acc = fmaf(sh_s[k+3], wv[i].w, acc);
            }
        }
        float hp = acc + b1[tid];                // bias added after
        sh_h[tid] = fmaxf(hp, 0.0f);             // relu
    }
    __syncthreads();

    // ---- stage 2: 1 channel/thread, exact seq-j chain ----
    float acc = 0.0f;
    #pragma unroll
    for (int q = 0; q < 4; ++q) {
        const int j4 = q * 4;
        acc = fmaf(sh_h[j4+0], w2r[q].x, acc);
        acc = fmaf(sh_h[j4+1], w2r[q].y, acc);
        acc = fmaf(sh_h[j4+2], w2r[q].z, acc);
        acc = fmaf(sh_h[j4+3], w2r[q].w, acc);
    }
    const float z  = acc + bias2;
    const float ef = (float)exp((double)(-z));  // ~correctly-rounded f32 exp
    const float g  = 1.0f / (1.0f + ef);        // f32 add, f32 div
    sh_g[tid] = g;
    __syncthreads();

    // ---- exact stable rank (descending, lower index wins ties) ----
    int r = 0;
    #pragma unroll 8
    for (int k = 0; k < NC; ++k) {
        const float gk = sh_g[k];
        r += (gk > g) || (gk == g && k < tid);
    }
    if (r == j) { sel_g = g; sel_c = tid; }   // ranks are a permutation: 1 hit
    __syncthreads();

    const int   c  = sel_c;
    const float gg = sel_g;

    // ---- gather + scale (round-6 body, bit-exact f32 mul) ----
    const float4* src = reinterpret_cast<const float4*>(
        x + ((size_t)(b * NC + c)) * HWPIX);
    float4* dst = reinterpret_cast<float4*>(out + (size_t)bid * HWPIX);

    float4 v;
    v = src[tid];       v.x *= gg; v.y *= gg; v.z *= gg; v.w *= gg; dst[tid]       = v;
    v = src[tid + 256]; v.x *= gg; v.y *= gg; v.z *= gg; v.w *= gg; dst[tid + 256] = v;
    v = src[tid + 512]; v.x *= gg; v.y *= gg; v.z *= gg; v.w *= gg; dst[tid + 512] = v;
    if (tid < 16) {
        v = src[tid + 768]; v.x *= gg; v.y *= gg; v.z *= gg; v.w *= gg; dst[tid + 768] = v;
    }
}

// ---------------------------------------------------------------------------
extern "C" void kernel_launch(void* const* d_in, const int* in_sizes, int n_in,
                              void* d_out, int out_size, void* d_ws, size_t ws_size,
                              hipStream_t stream) {
    const float* x  = (const float*)d_in[0];
    const float* w1 = (const float*)d_in[1];
    const float* b1 = (const float*)d_in[2];
    const float* w2 = (const float*)d_in[3];
    const float* b2 = (const float*)d_in[4];
    float* out = (float*)d_out;

    float* s_ws = (float*)d_ws;   // 8192 f32

    k_mean<<<32 * NC, 64, 0, stream>>>(x, s_ws);
    k_mlp_gather<<<32 * NCNEW, 256, 0, stream>>>(x, w1, b1, w2, b2, s_ws, out);
}

// Round 12
// 43.919 us; speedup vs baseline: 8.6271x; 1.4934x over previous
//
#include <hip/hip_runtime.h>
#include <math.h>

#define HWPIX 3136   // 56*56
#define NC    256
#define NCNEW 128
#define NH    16     // C/R

// ---------------------------------------------------------------------------
// numpy pairwise block sum (8 <= n <= 128) — exact np arithmetic order.
// ---------------------------------------------------------------------------
__device__ __forceinline__ float np_block_sum(const float* __restrict__ a, int n) {
    float r0=a[0],r1=a[1],r2=a[2],r3=a[3],r4=a[4],r5=a[5],r6=a[6],r7=a[7];
    int i = 8;
    const int lim = n - (n & 7);
    for (; i < lim; i += 8) {
        r0 += a[i+0]; r1 += a[i+1]; r2 += a[i+2]; r3 += a[i+3];
        r4 += a[i+4]; r5 += a[i+5]; r6 += a[i+6]; r7 += a[i+7];
    }
    float res = ((r0 + r1) + (r2 + r3)) + ((r4 + r5) + (r6 + r7));
    for (; i < n; ++i) res += a[i];
    return res;
}

// ---------------------------------------------------------------------------
// Kernel 1 (round-6 verbatim, passing, ~HBM floor): per-plane bitwise
// np.float32 mean. One 64-thread block per plane.
// ---------------------------------------------------------------------------
__global__ __launch_bounds__(64) void k_mean(const float* __restrict__ x,
                                             float* __restrict__ s) {
    const int plane = blockIdx.x;  // b*256 + c
    const int t = threadIdx.x;
    __shared__ float pl[HWPIX];

    const float4* src4 = reinterpret_cast<const float4*>(x + (size_t)plane * HWPIX);

    float4 va[13];
    #pragma unroll
    for (int i = 0; i < 12; ++i) va[i] = src4[i * 64 + t];
    {   int idx = 768 + t; if (idx > 783) idx = 783;
        va[12] = src4[idx];
    }
    #pragma unroll
    for (int i = 0; i < 12; ++i)
        *reinterpret_cast<float4*>(&pl[(i * 64 + t) * 4]) = va[i];
    if (t < 16)
        *reinterpret_cast<float4*>(&pl[(768 + t) * 4]) = va[12];
    __syncthreads();

    const int m    = t >> 1;
    const int base = 98 * m + ((t & 1) ? 48 : 0);
    const int n    = (t & 1) ? 50 : 48;
    float v = np_block_sum(pl + base, n);

    #pragma unroll
    for (int mask = 1; mask <= 32; mask <<= 1)
        v += __shfl_xor(v, mask, 64);

    if (t == 0) s[plane] = v / 3136.0f;
}

// ---------------------------------------------------------------------------
// Kernel 2: fused MLP + top-k + gather, one block per FOUR output planes
// (grid 1024). R11's redundancy cost (rank loop ~15us aggregate + chains,
// x4096 blocks) amortized 4x, and the rank compare packed into one u64:
//   key = (f32_bits(g) << 8) | (255 - c)
// g>0 so f32 bits are order-isomorphic; ties (equal g) resolve to the
// lower channel exactly like (gk==g && k<c). rank = #{key_k > key_mine}
// == the reference's stable descending rank, at 1 cmp per k.
// MLP arithmetic is byte-identical to the passing R11 code.
// ---------------------------------------------------------------------------
__global__ __launch_bounds__(256) void k_mlp_gather(const float* __restrict__ x,
                                                    const float* __restrict__ w1,
                                                    const float* __restrict__ b1,
                                                    const float* __restrict__ w2,
                                                    const float* __restrict__ b2,
                                                    const float* __restrict__ s_ws,
                                                    float* __restrict__ out) {
    const int bid = blockIdx.x;          // 0..1023
    const int b   = bid >> 5;            // batch 0..31
    const int j0  = (bid & 31) << 2;     // first of 4 output ranks
    const int tid = threadIdx.x;
    const int w   = tid >> 6;            // wave 0..3 -> plane j0+w
    const int t   = tid & 63;            // lane

    __shared__ float sh_s[NC];                     // 1 KB
    __shared__ float sh_h[NH];                     // 64 B
    __shared__ unsigned long long sh_key[NC];      // 2 KB
    __shared__ float sel_g[4];
    __shared__ int   sel_c[4];

    // prefetch bias2 + this thread's w2 row (consumed in exact j-order)
    const float bias2 = b2[tid];
    float4 w2r[4];
    #pragma unroll
    for (int q = 0; q < 4; ++q)
        w2r[q] = reinterpret_cast<const float4*>(w2)[tid * 4 + q];

    // stage s[b,*] into LDS (coalesced float4)
    if (tid < 64)
        reinterpret_cast<float4*>(sh_s)[tid] =
            reinterpret_cast<const float4*>(s_ws + b * NC)[tid];
    __syncthreads();

    // ---- stage 1: 16 lanes, exact seq-k fmaf chain, w1 row from global ----
    if (tid < NH) {
        const float4* w1r = reinterpret_cast<const float4*>(w1 + tid * NC);
        float acc = 0.0f;
        for (int kb = 0; kb < 8; ++kb) {        // 8 batches of 32 k-values
            float4 wv[8];
            #pragma unroll
            for (int i = 0; i < 8; ++i) wv[i] = w1r[kb * 8 + i];
            #pragma unroll
            for (int i = 0; i < 8; ++i) {
                const int k = kb * 32 + i * 4;
                acc = fmaf(sh_s[k+0], wv[i].x, acc);
                acc = fmaf(sh_s[k+1], wv[i].y, acc);
                acc = fmaf(sh_s[k+2], wv[i].z, acc);
                acc = fmaf(sh_s[k+3], wv[i].w, acc);
            }
        }
        float hp = acc + b1[tid];                // bias added after
        sh_h[tid] = fmaxf(hp, 0.0f);             // relu
    }
    __syncthreads();

    // ---- stage 2: 1 channel/thread, exact seq-j chain + cr-exp sigmoid ----
    float acc = 0.0f;
    #pragma unroll
    for (int q = 0; q < 4; ++q) {
        const int j4 = q * 4;
        acc = fmaf(sh_h[j4+0], w2r[q].x, acc);
        acc = fmaf(sh_h[j4+1], w2r[q].y, acc);
        acc = fmaf(sh_h[j4+2], w2r[q].z, acc);
        acc = fmaf(sh_h[j4+3], w2r[q].w, acc);
    }
    const float z  = acc + bias2;
    const float ef = (float)exp((double)(-z));  // ~correctly-rounded f32 exp
    const float g  = 1.0f / (1.0f + ef);        // f32 add, f32 div

    const unsigned long long mykey =
        ((unsigned long long)__float_as_uint(g) << 8) |
        (unsigned long long)(255 - tid);
    sh_key[tid] = mykey;
    __syncthreads();

    // ---- rank = count of strictly larger keys (exact stable descending) ----
    int r = 0;
    #pragma unroll 16
    for (int k = 0; k < NC; ++k)
        r += (sh_key[k] > mykey);

    if ((unsigned)(r - j0) < 4u) {    // this block owns ranks j0..j0+3
        sel_g[r - j0] = g;
        sel_c[r - j0] = tid;
    }
    __syncthreads();

    const int   c  = sel_c[w];        // wave w gathers rank j0+w
    const float gg = sel_g[w];

    // ---- gather + scale (bit-exact f32 mul), one plane per wave ----
    const float4* src = reinterpret_cast<const float4*>(
        x + ((size_t)(b * NC + c)) * HWPIX);
    float4* dst = reinterpret_cast<float4*>(
        out + (size_t)((b << 7) | (j0 + w)) * HWPIX);

    float4 va[13];
    #pragma unroll
    for (int i = 0; i < 12; ++i) va[i] = src[i * 64 + t];
    {   int ii = 768 + t; if (ii > 783) ii = 783;
        va[12] = src[ii];
    }
    #pragma unroll
    for (int i = 0; i < 12; ++i) {
        float4 v = va[i];
        v.x *= gg; v.y *= gg; v.z *= gg; v.w *= gg;
        dst[i * 64 + t] = v;
    }
    if (t < 16) {
        float4 v = va[12];
        v.x *= gg; v.y *= gg; v.z *= gg; v.w *= gg;
        dst[768 + t] = v;
    }
}

// ---------------------------------------------------------------------------
extern "C" void kernel_launch(void* const* d_in, const int* in_sizes, int n_in,
                              void* d_out, int out_size, void* d_ws, size_t ws_size,
                              hipStream_t stream) {
    const float* x  = (const float*)d_in[0];
    const float* w1 = (const float*)d_in[1];
    const float* b1 = (const float*)d_in[2];
    const float* w2 = (const float*)d_in[3];
    const float* b2 = (const float*)d_in[4];
    float* out = (float*)d_out;

    float* s_ws = (float*)d_ws;   // 8192 f32

    k_mean<<<32 * NC, 64, 0, stream>>>(x, s_ws);
    k_mlp_gather<<<1024, 256, 0, stream>>>(x, w1, b1, w2, b2, s_ws, out);
}

// Round 13
// 42.656 us; speedup vs baseline: 8.8825x; 1.0296x over previous
//
#include <hip/hip_runtime.h>
#include <math.h>

#define HWPIX 3136   // 56*56
#define NC    256
#define NCNEW 128
#define NH    16     // C/R

// ---------------------------------------------------------------------------
// numpy pairwise block sum (8 <= n <= 128) — exact np arithmetic order.
// ---------------------------------------------------------------------------
__device__ __forceinline__ float np_block_sum(const float* __restrict__ a, int n) {
    float r0=a[0],r1=a[1],r2=a[2],r3=a[3],r4=a[4],r5=a[5],r6=a[6],r7=a[7];
    int i = 8;
    const int lim = n - (n & 7);
    for (; i < lim; i += 8) {
        r0 += a[i+0]; r1 += a[i+1]; r2 += a[i+2]; r3 += a[i+3];
        r4 += a[i+4]; r5 += a[i+5]; r6 += a[i+6]; r7 += a[i+7];
    }
    float res = ((r0 + r1) + (r2 + r3)) + ((r4 + r5) + (r6 + r7));
    for (; i < n; ++i) res += a[i];
    return res;
}

// ---------------------------------------------------------------------------
// Kernel 1 (round-6 verbatim, passing, ~HBM floor): per-plane bitwise
// np.float32 mean. One 64-thread block per plane.
// ---------------------------------------------------------------------------
__global__ __launch_bounds__(64) void k_mean(const float* __restrict__ x,
                                             float* __restrict__ s) {
    const int plane = blockIdx.x;  // b*256 + c
    const int t = threadIdx.x;
    __shared__ float pl[HWPIX];

    const float4* src4 = reinterpret_cast<const float4*>(x + (size_t)plane * HWPIX);

    float4 va[13];
    #pragma unroll
    for (int i = 0; i < 12; ++i) va[i] = src4[i * 64 + t];
    {   int idx = 768 + t; if (idx > 783) idx = 783;
        va[12] = src4[idx];
    }
    #pragma unroll
    for (int i = 0; i < 12; ++i)
        *reinterpret_cast<float4*>(&pl[(i * 64 + t) * 4]) = va[i];
    if (t < 16)
        *reinterpret_cast<float4*>(&pl[(768 + t) * 4]) = va[12];
    __syncthreads();

    const int m    = t >> 1;
    const int base = 98 * m + ((t & 1) ? 48 : 0);
    const int n    = (t & 1) ? 50 : 48;
    float v = np_block_sum(pl + base, n);

    #pragma unroll
    for (int mask = 1; mask <= 32; mask <<= 1)
        v += __shfl_xor(v, mask, 64);

    if (t == 0) s[plane] = v / 3136.0f;
}

// ---------------------------------------------------------------------------
// Kernel 2: fused MLP + top-k + gather, one block per EIGHT output planes
// (grid 512 x 512 threads). R12's redundant MLP+rank (was x1024 blocks)
// halved again; preamble amortized over 2x memory work. MLP arithmetic is
// byte-identical to the passing R12 code (threads 256..511 idle through
// the MLP phases and join for the gather). u64 key rank:
//   key = (f32_bits(g) << 8) | (255 - c)   (g>0 -> order-isomorphic,
// ties -> lower channel first) == reference's stable descending rank.
// ---------------------------------------------------------------------------
__global__ __launch_bounds__(512) void k_mlp_gather(const float* __restrict__ x,
                                                    const float* __restrict__ w1,
                                                    const float* __restrict__ b1,
                                                    const float* __restrict__ w2,
                                                    const float* __restrict__ b2,
                                                    const float* __restrict__ s_ws,
                                                    float* __restrict__ out) {
    const int bid = blockIdx.x;          // 0..511
    const int b   = bid >> 4;            // batch 0..31
    const int j0  = (bid & 15) << 3;     // first of 8 output ranks
    const int tid = threadIdx.x;         // 0..511
    const int w   = tid >> 6;            // wave 0..7 -> plane j0+w
    const int t   = tid & 63;            // lane

    __shared__ float sh_s[NC];                     // 1 KB
    __shared__ float sh_h[NH];                     // 64 B
    __shared__ unsigned long long sh_key[NC];      // 2 KB
    __shared__ float sel_g[8];
    __shared__ int   sel_c[8];

    // prefetch bias2 + this thread's w2 row (consumed in exact j-order)
    float bias2 = 0.0f;
    float4 w2r[4];
    if (tid < NC) {
        bias2 = b2[tid];
        #pragma unroll
        for (int q = 0; q < 4; ++q)
            w2r[q] = reinterpret_cast<const float4*>(w2)[tid * 4 + q];
    }

    // stage s[b,*] into LDS (coalesced float4)
    if (tid < 64)
        reinterpret_cast<float4*>(sh_s)[tid] =
            reinterpret_cast<const float4*>(s_ws + b * NC)[tid];
    __syncthreads();

    // ---- stage 1: 16 lanes, exact seq-k fmaf chain, w1 row from global ----
    if (tid < NH) {
        const float4* w1r = reinterpret_cast<const float4*>(w1 + tid * NC);
        float acc = 0.0f;
        for (int kb = 0; kb < 8; ++kb) {        // 8 batches of 32 k-values
            float4 wv[8];
            #pragma unroll
            for (int i = 0; i < 8; ++i) wv[i] = w1r[kb * 8 + i];
            #pragma unroll
            for (int i = 0; i < 8; ++i) {
                const int k = kb * 32 + i * 4;
                acc = fmaf(sh_s[k+0], wv[i].x, acc);
                acc = fmaf(sh_s[k+1], wv[i].y, acc);
                acc = fmaf(sh_s[k+2], wv[i].z, acc);
                acc = fmaf(sh_s[k+3], wv[i].w, acc);
            }
        }
        float hp = acc + b1[tid];                // bias added after
        sh_h[tid] = fmaxf(hp, 0.0f);             // relu
    }
    __syncthreads();

    // ---- stage 2 + rank: threads 0..255 only -------------------------------
    if (tid < NC) {
        float acc = 0.0f;
        #pragma unroll
        for (int q = 0; q < 4; ++q) {
            const int j4 = q * 4;
            acc = fmaf(sh_h[j4+0], w2r[q].x, acc);
            acc = fmaf(sh_h[j4+1], w2r[q].y, acc);
            acc = fmaf(sh_h[j4+2], w2r[q].z, acc);
            acc = fmaf(sh_h[j4+3], w2r[q].w, acc);
        }
        const float z  = acc + bias2;
        const float ef = (float)exp((double)(-z));  // ~cr f32 exp
        const float g  = 1.0f / (1.0f + ef);        // f32 add, f32 div

        const unsigned long long mykey =
            ((unsigned long long)__float_as_uint(g) << 8) |
            (unsigned long long)(255 - tid);
        sh_key[tid] = mykey;
        __syncthreads();

        // rank = count of strictly larger keys (exact stable descending)
        int r = 0;
        #pragma unroll 16
        for (int k = 0; k < NC; ++k)
            r += (sh_key[k] > mykey);

        if ((unsigned)(r - j0) < 8u) {    // this block owns ranks j0..j0+7
            sel_g[r - j0] = g;
            sel_c[r - j0] = tid;
        }
    } else {
        __syncthreads();   // matching barrier for tid >= 256
    }
    __syncthreads();

    const int   c  = sel_c[w];        // wave w gathers rank j0+w
    const float gg = sel_g[w];

    // ---- gather + scale (bit-exact f32 mul), one plane per wave ----
    const float4* src = reinterpret_cast<const float4*>(
        x + ((size_t)(b * NC + c)) * HWPIX);
    float4* dst = reinterpret_cast<float4*>(
        out + (size_t)((b << 7) | (j0 + w)) * HWPIX);

    float4 va[13];
    #pragma unroll
    for (int i = 0; i < 12; ++i) va[i] = src[i * 64 + t];
    {   int ii = 768 + t; if (ii > 783) ii = 783;
        va[12] = src[ii];
    }
    #pragma unroll
    for (int i = 0; i < 12; ++i) {
        float4 v = va[i];
        v.x *= gg; v.y *= gg; v.z *= gg; v.w *= gg;
        dst[i * 64 + t] = v;
    }
    if (t < 16) {
        float4 v = va[12];
        v.x *= gg; v.y *= gg; v.z *= gg; v.w *= gg;
        dst[768 + t] = v;
    }
}

// ---------------------------------------------------------------------------
extern "C" void kernel_launch(void* const* d_in, const int* in_sizes, int n_in,
                              void* d_out, int out_size, void* d_ws, size_t ws_size,
                              hipStream_t stream) {
    const float* x  = (const float*)d_in[0];
    const float* w1 = (const float*)d_in[1];
    const float* b1 = (const float*)d_in[2];
    const float* w2 = (const float*)d_in[3];
    const float* b2 = (const float*)d_in[4];
    float* out = (float*)d_out;

    float* s_ws = (float*)d_ws;   // 8192 f32

    k_mean<<<32 * NC, 64, 0, stream>>>(x, s_ws);
    k_mlp_gather<<<512, 512, 0, stream>>>(x, w1, b1, w2, b2, s_ws, out);
}

// Round 14
// 42.439 us; speedup vs baseline: 8.9278x; 1.0051x over previous
//
#include <hip/hip_runtime.h>
#include <math.h>

#define HWPIX 3136   // 56*56
#define NC    256
#define NCNEW 128
#define NH    16     // C/R

// ---------------------------------------------------------------------------
// numpy pairwise block sum (8 <= n <= 128) — exact np arithmetic order.
// ---------------------------------------------------------------------------
__device__ __forceinline__ float np_block_sum(const float* __restrict__ a, int n) {
    float r0=a[0],r1=a[1],r2=a[2],r3=a[3],r4=a[4],r5=a[5],r6=a[6],r7=a[7];
    int i = 8;
    const int lim = n - (n & 7);
    for (; i < lim; i += 8) {
        r0 += a[i+0]; r1 += a[i+1]; r2 += a[i+2]; r3 += a[i+3];
        r4 += a[i+4]; r5 += a[i+5]; r6 += a[i+6]; r7 += a[i+7];
    }
    float res = ((r0 + r1) + (r2 + r3)) + ((r4 + r5) + (r6 + r7));
    for (; i < n; ++i) res += a[i];
    return res;
}

// ---------------------------------------------------------------------------
// Kernel 1 (round-6 verbatim, passing, measured ~97% of read BW ceiling):
// per-plane bitwise np.float32 mean. One 64-thread block per plane.
// ---------------------------------------------------------------------------
__global__ __launch_bounds__(64) void k_mean(const float* __restrict__ x,
                                             float* __restrict__ s) {
    const int plane = blockIdx.x;  // b*256 + c
    const int t = threadIdx.x;
    __shared__ float pl[HWPIX];

    const float4* src4 = reinterpret_cast<const float4*>(x + (size_t)plane * HWPIX);

    float4 va[13];
    #pragma unroll
    for (int i = 0; i < 12; ++i) va[i] = src4[i * 64 + t];
    {   int idx = 768 + t; if (idx > 783) idx = 783;
        va[12] = src4[idx];
    }
    #pragma unroll
    for (int i = 0; i < 12; ++i)
        *reinterpret_cast<float4*>(&pl[(i * 64 + t) * 4]) = va[i];
    if (t < 16)
        *reinterpret_cast<float4*>(&pl[(768 + t) * 4]) = va[12];
    __syncthreads();

    const int m    = t >> 1;
    const int base = 98 * m + ((t & 1) ? 48 : 0);
    const int n    = (t & 1) ? 50 : 48;
    float v = np_block_sum(pl + base, n);

    #pragma unroll
    for (int mask = 1; mask <= 32; mask <<= 1)
        v += __shfl_xor(v, mask, 64);

    if (t == 0) s[plane] = v / 3136.0f;
}

// ---------------------------------------------------------------------------
// Kernel 2: fused MLP + top-k + gather, one block per SIXTEEN output planes
// (grid 256 x 1024 threads = 1 block/CU, minimum possible MLP replication
// while keeping all CUs busy). MLP+rank code byte-identical to the
// twice-passing R12/R13 version (threads 256..1023 idle through the MLP
// phases, matching barrier counts, then join for the gather).
// u64 key rank: key = (f32_bits(g) << 8) | (255 - c); g>0 so f32 bits are
// order-isomorphic, ties resolve to lower channel == np stable descending.
// ---------------------------------------------------------------------------
__global__ __launch_bounds__(1024) void k_mlp_gather(const float* __restrict__ x,
                                                     const float* __restrict__ w1,
                                                     const float* __restrict__ b1,
                                                     const float* __restrict__ w2,
                                                     const float* __restrict__ b2,
                                                     const float* __restrict__ s_ws,
                                                     float* __restrict__ out) {
    const int bid = blockIdx.x;          // 0..255
    const int b   = bid >> 3;            // batch 0..31
    const int j0  = (bid & 7) << 4;      // first of 16 output ranks
    const int tid = threadIdx.x;         // 0..1023
    const int w   = tid >> 6;            // wave 0..15 -> plane j0+w
    const int t   = tid & 63;            // lane

    __shared__ float sh_s[NC];                     // 1 KB
    __shared__ float sh_h[NH];                     // 64 B
    __shared__ unsigned long long sh_key[NC];      // 2 KB
    __shared__ float sel_g[16];
    __shared__ int   sel_c[16];

    // prefetch bias2 + this thread's w2 row (consumed in exact j-order)
    float bias2 = 0.0f;
    float4 w2r[4];
    if (tid < NC) {
        bias2 = b2[tid];
        #pragma unroll
        for (int q = 0; q < 4; ++q)
            w2r[q] = reinterpret_cast<const float4*>(w2)[tid * 4 + q];
    }

    // stage s[b,*] into LDS (coalesced float4)
    if (tid < 64)
        reinterpret_cast<float4*>(sh_s)[tid] =
            reinterpret_cast<const float4*>(s_ws + b * NC)[tid];
    __syncthreads();

    // ---- stage 1: 16 lanes, exact seq-k fmaf chain, w1 row from global ----
    if (tid < NH) {
        const float4* w1r = reinterpret_cast<const float4*>(w1 + tid * NC);
        float acc = 0.0f;
        for (int kb = 0; kb < 8; ++kb) {        // 8 batches of 32 k-values
            float4 wv[8];
            #pragma unroll
            for (int i = 0; i < 8; ++i) wv[i] = w1r[kb * 8 + i];
            #pragma unroll
            for (int i = 0; i < 8; ++i) {
                const int k = kb * 32 + i * 4;
                acc = fmaf(sh_s[k+0], wv[i].x, acc);
                acc = fmaf(sh_s[k+1], wv[i].y, acc);
                acc = fmaf(sh_s[k+2], wv[i].z, acc);
                acc = fmaf(sh_s[k+3], wv[i].w, acc);
            }
        }
        float hp = acc + b1[tid];                // bias added after
        sh_h[tid] = fmaxf(hp, 0.0f);             // relu
    }
    __syncthreads();

    // ---- stage 2 + rank: threads 0..255 only -------------------------------
    if (tid < NC) {
        float acc = 0.0f;
        #pragma unroll
        for (int q = 0; q < 4; ++q) {
            const int j4 = q * 4;
            acc = fmaf(sh_h[j4+0], w2r[q].x, acc);
            acc = fmaf(sh_h[j4+1], w2r[q].y, acc);
            acc = fmaf(sh_h[j4+2], w2r[q].z, acc);
            acc = fmaf(sh_h[j4+3], w2r[q].w, acc);
        }
        const float z  = acc + bias2;
        const float ef = (float)exp((double)(-z));  // ~cr f32 exp
        const float g  = 1.0f / (1.0f + ef);        // f32 add, f32 div

        const unsigned long long mykey =
            ((unsigned long long)__float_as_uint(g) << 8) |
            (unsigned long long)(255 - tid);
        sh_key[tid] = mykey;
        __syncthreads();

        // rank = count of strictly larger keys (exact stable descending)
        int r = 0;
        #pragma unroll 16
        for (int k = 0; k < NC; ++k)
            r += (sh_key[k] > mykey);

        if ((unsigned)(r - j0) < 16u) {   // this block owns ranks j0..j0+15
            sel_g[r - j0] = g;
            sel_c[r - j0] = tid;
        }
    } else {
        __syncthreads();   // matching barrier for tid >= 256
    }
    __syncthreads();

    const int   c  = sel_c[w];        // wave w gathers rank j0+w
    const float gg = sel_g[w];

    // ---- gather + scale (bit-exact f32 mul), one plane per wave ----
    const float4* src = reinterpret_cast<const float4*>(
        x + ((size_t)(b * NC + c)) * HWPIX);
    float4* dst = reinterpret_cast<float4*>(
        out + (size_t)((b << 7) | (j0 + w)) * HWPIX);

    float4 va[13];
    #pragma unroll
    for (int i = 0; i < 12; ++i) va[i] = src[i * 64 + t];
    {   int ii = 768 + t; if (ii > 783) ii = 783;
        va[12] = src[ii];
    }
    #pragma unroll
    for (int i = 0; i < 12; ++i) {
        float4 v = va[i];
        v.x *= gg; v.y *= gg; v.z *= gg; v.w *= gg;
        dst[i * 64 + t] = v;
    }
    if (t < 16) {
        float4 v = va[12];
        v.x *= gg; v.y *= gg; v.z *= gg; v.w *= gg;
        dst[768 + t] = v;
    }
}

// ---------------------------------------------------------------------------
extern "C" void kernel_launch(void* const* d_in, const int* in_sizes, int n_in,
                              void* d_out, int out_size, void* d_ws, size_t ws_size,
                              hipStream_t stream) {
    const float* x  = (const float*)d_in[0];
    const float* w1 = (const float*)d_in[1];
    const float* b1 = (const float*)d_in[2];
    const float* w2 = (const float*)d_in[3];
    const float* b2 = (const float*)d_in[4];
    float* out = (float*)d_out;

    float* s_ws = (float*)d_ws;   // 8192 f32

    k_mean<<<32 * NC, 64, 0, stream>>>(x, s_ws);
    k_mlp_gather<<<256, 1024, 0, stream>>>(x, w1, b1, w2, b2, s_ws, out);
}